// Round 5
// baseline (278.337 us; speedup 1.0000x reference)
//
#include <hip/hip_runtime.h>
#include <cstdint>
#include <cstddef>

// GraphSAGE 3-layer, N=100000 nodes, E=1600000 edges, dims 64->64->64->32.
// Transform-then-aggregate; padded CSR via 256-node super-buckets;
// weights pre-swizzled once into MFMA B-frag layout (tail blocks of bin);
// per-layer dual GEMMs (t=h@Wl, r=h@Wr+b, mfma_f32_16x16x32_bf16) LDS-free,
// barrier-free; t for layers 0/1 fp8 e4m3 (row=64B=1 line), t2 bf16;
// r bf16 L0/L1, fp32 L2.
// R17: revert R16's 4-lane gather (halved wave count = halved MLP -> +12us;
//      gathers are latency-bound, keep 8 lanes/node x 8B); keep packed meta
//      + colidx prefetch; NEW: degree-sort nodes within each super-bucket
//      (LDS counting sort in CSR pass) -> slot-ordered int4 meta
//      (rowstart, pc|deg<<16, node); waves process 8 equal-degree nodes,
//      killing the ~35% max-of-8 Poisson imbalance. X/out writes scattered
//      by node id but full-line (64/128B rows). X stores back to PLAIN
//      (R16 nt store forced gemm1 HBM refetch).
// R16: 4-lane gather REGRESSED (+12us) — wave count is the MLP lever.
// R15: half-tables + 2-pass gather REGRESSED (+49us) — gathers latency-
//      bound (22% BW, 22% VALU, 54% occ); traffic is not the limit.
// R14: csr+gemm0 merged; pad-4 CSR. -12us (boundary ~3.5us each).
// R13: pad-8 sentinel CSR; r bf16 L0/L1. gathers NOT divergence-bound.
// R4: LDS-atomic aggregation is 12x slower than CSR gather — don't revisit.
// R6: per-node scatter -> 64B-line write amplification, keep super-buckets.
// R10: gather+GEMM fusion halves occupancy, couples imbalance — keep split.
// R12: R11's "slow GEMM" was broken weight staging; fp8 gather is the win.

constexpr int SBW = 256;     // dst nodes per super-bucket
constexpr int LOGSBW = 8;
constexpr int CAPS = 4608;   // super capacity (unpadded); mean 4096, +8 sigma
constexpr int CAPSP = 5632;  // padded capacity; mean ~4608 (pad-4), %16==0
constexpr int CHK = 2048;    // edges per bin block -> 782 blocks

typedef __attribute__((ext_vector_type(8))) short s16x8;
typedef __attribute__((ext_vector_type(4))) float f32x4;
typedef __attribute__((ext_vector_type(2))) float f32x2;
typedef __attribute__((ext_vector_type(4))) int i32x4;

__device__ inline unsigned short f2bf(float f) {
  unsigned u = __builtin_bit_cast(unsigned, f);
  u += 0x7FFFu + ((u >> 16) & 1u);          // round-to-nearest-even
  return (unsigned short)(u >> 16);
}
__device__ inline float bf2f(unsigned short b) {
  unsigned u = ((unsigned)b) << 16;
  return __builtin_bit_cast(float, u);
}
__device__ inline unsigned char f2fp8(float f) {
  int p = __builtin_amdgcn_cvt_pk_fp8_f32(f, f, 0, false);
  return (unsigned char)(p & 0xFF);
}

// ------- init: zero bcur (1 block) ----------------------------------------

__global__ __launch_bounds__(256) void zero_bcur(int* __restrict__ bcur, int NSB) {
  for (int i = threadIdx.x; i < NSB; i += 256) bcur[i] = 0;
}

// ------- pass 1: coarse bin (blocks [0,bbl)) + weight swizzle tail ---------
// Swizzle: per layer 2*NTT tiles (Wl then Wr); per tile 2 planes (k<32,
// k>=32); per plane 64 lanes x 8 bf16: W[k=plane*32+q*8+j][col=c*16+m].
// Layer short offsets: L0=0, L1=8192, L2=16384. gemm fetch:
// frag = Wsw[off + (c*2+plane)*512 + lane*8 ..+8] (16B/lane, coalesced).

__global__ __launch_bounds__(256) void bin_stage(const int* __restrict__ src,
                                                 const int* __restrict__ dst,
                                                 int* __restrict__ bcur,
                                                 unsigned int* __restrict__ coarse,
                                                 int NSB, int E,
                                                 const float* __restrict__ Wl0,
                                                 const float* __restrict__ Wr0,
                                                 const float* __restrict__ Wl1,
                                                 const float* __restrict__ Wr1,
                                                 const float* __restrict__ Wl2,
                                                 const float* __restrict__ Wr2,
                                                 unsigned short* __restrict__ Wsw) {
  __shared__ int h[512];
  __shared__ unsigned ed[CHK];
  __shared__ short sb[CHK];
  const int tid = threadIdx.x;
  const int bbl = (E + CHK - 1) / CHK;
  if ((int)blockIdx.x >= bbl) {
    // ---- weight swizzle path ----
    int g = (blockIdx.x - bbl) * 256 + tid;    // u32 index
    if (g >= 10240) return;
    int s = g * 2;                             // short index (j even)
    int layer, off;
    if (s < 8192)       { layer = 0; off = 0; }
    else if (s < 16384) { layer = 1; off = 8192; }
    else                { layer = 2; off = 16384; }
    int t = s - off;
    int D = (layer == 2) ? 32 : 64;
    int NTT = D / 16;
    int tt = t >> 10;
    int rem = t & 1023;
    int plane = rem >> 9;
    int rem2 = rem & 511;
    int lane = rem2 >> 3;
    int j = rem2 & 7;
    int q = lane >> 4, m = lane & 15;
    int k = plane * 32 + q * 8 + j;
    const float* W;
    int c;
    if (tt < NTT) {
      c = tt;
      W = (layer == 0) ? Wl0 : (layer == 1) ? Wl1 : Wl2;
    } else {
      c = tt - NTT;
      W = (layer == 0) ? Wr0 : (layer == 1) ? Wr1 : Wr2;
    }
    int col = c * 16 + m;
    unsigned lo = f2bf(W[k * D + col]);
    unsigned hi = f2bf(W[(k + 1) * D + col]);
    *(unsigned*)&Wsw[s] = lo | (hi << 16);
    return;
  }
  // ---- binning path ----
  for (int i = tid; i < NSB; i += 256) h[i] = 0;
  __syncthreads();
  const int e0 = blockIdx.x * CHK;
  const int e1 = min(E, e0 + CHK);
  for (int e = e0 + tid; e < e1; e += 256) {
    int d = dst[e];
    int s = src[e];
    int b = d >> LOGSBW;
    ed[e - e0] = (unsigned)s | ((unsigned)(d & (SBW - 1)) << 17);
    sb[e - e0] = (short)b;
    atomicAdd(&h[b], 1);
  }
  __syncthreads();
  for (int i = tid; i < NSB; i += 256) {
    int c = h[i];
    h[i] = c ? (i * CAPS + atomicAdd(&bcur[i], c)) : 0;  // slot -> abs cursor
  }
  __syncthreads();
  const int n = e1 - e0;
  for (int k = tid; k < n; k += 256) {
    int b = sb[k];
    int pos = atomicAdd(&h[b], 1);
    if (pos < (b + 1) * CAPS)                 // overflow guard (never taken)
      coarse[pos] = ed[k];
  }
}

// ------- pass 2: per-super count/scan/DEGREE-SORT -> padded CSR + meta, ---
// ------- merged with layer-0 dual GEMM (fills the idle CUs) ---------------
// CSR blocks [0,NSB): segments padded to x4, sentinel colidx=N (t row N is
// zero). LDS counting-sort by degree -> slot-ordered meta int4 =
// (rowstart, pc|deg<<16, node, 0); invalid slots (gn>=N) sort last with
// node=gn>=N so gathers early-out.
// GEMM0 blocks [NSB,NSB+gb): fp32 x -> t0 fp8 + r0 bf16.
// C/D layout: col=lane&15, row=(lane>>4)*4+reg (m89-verified).

__global__ __launch_bounds__(256) void csr_gemm0(const unsigned int* __restrict__ coarse,
                                                 const int* __restrict__ bcur,
                                                 int4* __restrict__ metaS,
                                                 int* __restrict__ colidx,
                                                 const float* __restrict__ x,
                                                 const unsigned short* __restrict__ Wf,
                                                 const float* __restrict__ bias,
                                                 unsigned char* __restrict__ t_out,
                                                 unsigned short* __restrict__ r_out,
                                                 int N, int NSB) {
  __shared__ int cnt[SBW];
  __shared__ int sc[SBW];
  __shared__ int cur[SBW];
  __shared__ int hist[64];
  __shared__ int sc64[64];
  __shared__ int hcur[64];
  const int tid = threadIdx.x;
  if ((int)blockIdx.x < NSB) {
    // ---------------- CSR + degree-sort path ----------------
    const int b = blockIdx.x;
    cnt[tid] = 0;
    if (tid < 64) hist[tid] = 0;
    __syncthreads();
    const int ec = min(bcur[b], CAPS);
    const int baseC = b * CAPS;
    const int baseP = b * CAPSP;
    for (int e = tid; e < ec; e += 256)
      atomicAdd(&cnt[coarse[baseC + e] >> 17], 1);
    __syncthreads();
    int v = cnt[tid];
    int pc = (v + 3) & ~3;                      // padded count (x4)
    sc[tid] = pc;
    const int gn = b * SBW + tid;
    const bool valid = gn < N;
    const int d = valid ? (v < 62 ? v : 62) : 63;
    atomicAdd(&hist[d], 1);
    __syncthreads();
    for (int off = 1; off < SBW; off <<= 1) {
      int y = sc[tid];
      if (tid >= off) y += sc[tid - off];
      __syncthreads();
      sc[tid] = y;
      __syncthreads();
    }
    int pex = sc[tid] - pc;                     // exclusive padded prefix
    cur[tid] = pex;
    // 64-bin exclusive scan of hist
    if (tid < 64) sc64[tid] = hist[tid];
    __syncthreads();
    for (int off = 1; off < 64; off <<= 1) {
      int y = 0;
      if (tid < 64) { y = sc64[tid]; if (tid >= off) y += sc64[tid - off]; }
      __syncthreads();
      if (tid < 64) sc64[tid] = y;
      __syncthreads();
    }
    if (tid < 64) hcur[tid] = sc64[tid] - hist[tid];
    __syncthreads();
    int rank = atomicAdd(&hcur[d], 1);
    metaS[b * SBW + rank] = make_int4(baseP + pex, pc | (v << 16), gn, 0);
    // scatter edges into degree-grouped... no: colidx layout stays by tid
    for (int e = tid; e < ec; e += 256) {
      unsigned p = coarse[baseC + e];
      int dl = (int)(p >> 17);
      int s = (int)(p & 0x1FFFFu);
      int l = atomicAdd(&cur[dl], 1);
      if (l < CAPSP)                            // overflow guard (never taken)
        colidx[baseP + l] = s;
    }
    // sentinel padding (disjoint from scatter range, no sync needed)
    int pe = pex + pc;
    if (pe > CAPSP) pe = CAPSP;
    for (int l = pex + v; l < pe; ++l) colidx[baseP + l] = N;
    return;
  }
  // ---------------- GEMM0 path ----------------
  constexpr int DOUT = 64;
  constexpr int NTT = 4;
  const int gbid = blockIdx.x - NSB;
  if (gbid == 0 && tid < 16)                   // zero sentinel row N of t
    ((unsigned*)t_out)[(size_t)N * 16 + tid] = 0u;
  const int wv = tid >> 6, lane = tid & 63;
  const int q = lane >> 4, m = lane & 15;
  const int row = gbid * 64 + wv * 16 + m;
  const int rowc = row < N ? row : N - 1;
  const float* xp = &x[(size_t)rowc * 64];
  float4 f0 = *(const float4*)&xp[q * 8];
  float4 f1 = *(const float4*)&xp[q * 8 + 4];
  float4 f2 = *(const float4*)&xp[32 + q * 8];
  float4 f3 = *(const float4*)&xp[32 + q * 8 + 4];
  s16x8 a0, a1;
  a0[0] = (short)f2bf(f0.x); a0[1] = (short)f2bf(f0.y);
  a0[2] = (short)f2bf(f0.z); a0[3] = (short)f2bf(f0.w);
  a0[4] = (short)f2bf(f1.x); a0[5] = (short)f2bf(f1.y);
  a0[6] = (short)f2bf(f1.z); a0[7] = (short)f2bf(f1.w);
  a1[0] = (short)f2bf(f2.x); a1[1] = (short)f2bf(f2.y);
  a1[2] = (short)f2bf(f2.z); a1[3] = (short)f2bf(f2.w);
  a1[4] = (short)f2bf(f3.x); a1[5] = (short)f2bf(f3.y);
  a1[6] = (short)f2bf(f3.z); a1[7] = (short)f2bf(f3.w);

  f32x4 acc[2 * NTT];
#pragma unroll
  for (int c = 0; c < 2 * NTT; ++c) acc[c] = (f32x4){0.f, 0.f, 0.f, 0.f};
#pragma unroll
  for (int c = 0; c < 2 * NTT; ++c) {
    s16x8 b0 = *(const s16x8*)&Wf[(c * 2 + 0) * 512 + lane * 8];
    s16x8 b1 = *(const s16x8*)&Wf[(c * 2 + 1) * 512 + lane * 8];
    acc[c] = __builtin_amdgcn_mfma_f32_16x16x32_bf16(a0, b0, acc[c], 0, 0, 0);
    acc[c] = __builtin_amdgcn_mfma_f32_16x16x32_bf16(a1, b1, acc[c], 0, 0, 0);
  }

  const int orow = gbid * 64 + wv * 16 + q * 4;
#pragma unroll
  for (int c = 0; c < NTT; ++c) {
#pragma unroll
    for (int i = 0; i < 4; ++i) {
      int r_ = orow + i;
      if (r_ < N) t_out[(size_t)r_ * DOUT + c * 16 + m] = f2fp8(acc[c][i]);
    }
  }
#pragma unroll
  for (int c = 0; c < NTT; ++c) {
    float bv = bias[c * 16 + m];
#pragma unroll
    for (int i = 0; i < 4; ++i) {
      int r_ = orow + i;
      if (r_ < N) r_out[(size_t)r_ * 64 + c * 16 + m] = f2bf(acc[NTT + c][i] + bv);
    }
  }
}

// ------- mid/final MFMA dual GEMM, bf16 input, LDS-free --------------------
// TFP8: t out fp8 (layer 1) else bf16 (layer 2). RB16: r out bf16 else fp32.

template <int DOUT, bool TFP8, bool RB16>
__global__ __launch_bounds__(256) void gemm_mfma(const unsigned short* __restrict__ Hm,
                                                 const unsigned short* __restrict__ Wf,
                                                 const float* __restrict__ bias,
                                                 void* __restrict__ t_out,
                                                 void* __restrict__ r_out, int N) {
  constexpr int NTT = DOUT / 16;
  constexpr int ROWB = TFP8 ? DOUT : DOUT * 2;   // t row bytes (always 64 here)
  const int tid = threadIdx.x;
  if (blockIdx.x == 0 && tid < ROWB / 4)        // zero sentinel row N of t
    ((unsigned*)((char*)t_out + (size_t)N * ROWB))[tid] = 0u;
  const int wv = tid >> 6, lane = tid & 63;
  const int q = lane >> 4, m = lane & 15;
  const int row = blockIdx.x * 64 + wv * 16 + m;
  const int rowc = row < N ? row : N - 1;
  const s16x8 a0 = *(const s16x8*)&Hm[(size_t)rowc * 64 + q * 8];
  const s16x8 a1 = *(const s16x8*)&Hm[(size_t)rowc * 64 + 32 + q * 8];

  f32x4 acc[2 * NTT];
#pragma unroll
  for (int c = 0; c < 2 * NTT; ++c) acc[c] = (f32x4){0.f, 0.f, 0.f, 0.f};
#pragma unroll
  for (int c = 0; c < 2 * NTT; ++c) {
    s16x8 b0 = *(const s16x8*)&Wf[(c * 2 + 0) * 512 + lane * 8];
    s16x8 b1 = *(const s16x8*)&Wf[(c * 2 + 1) * 512 + lane * 8];
    acc[c] = __builtin_amdgcn_mfma_f32_16x16x32_bf16(a0, b0, acc[c], 0, 0, 0);
    acc[c] = __builtin_amdgcn_mfma_f32_16x16x32_bf16(a1, b1, acc[c], 0, 0, 0);
  }

  const int orow = blockIdx.x * 64 + wv * 16 + q * 4;
#pragma unroll
  for (int c = 0; c < NTT; ++c) {
#pragma unroll
    for (int i = 0; i < 4; ++i) {
      int r_ = orow + i;
      if (r_ < N) {
        if (TFP8)
          ((unsigned char*)t_out)[(size_t)r_ * DOUT + c * 16 + m] = f2fp8(acc[c][i]);
        else
          ((unsigned short*)t_out)[(size_t)r_ * DOUT + c * 16 + m] = f2bf(acc[c][i]);
      }
    }
  }
#pragma unroll
  for (int c = 0; c < NTT; ++c) {
    float bv = bias[c * 16 + m];
#pragma unroll
    for (int i = 0; i < 4; ++i) {
      int r_ = orow + i;
      if (r_ < N) {
        if (RB16)
          ((unsigned short*)r_out)[(size_t)r_ * DOUT + c * 16 + m] =
              f2bf(acc[NTT + c][i] + bv);
        else
          ((float*)r_out)[(size_t)r_ * DOUT + c * 16 + m] = acc[NTT + c][i] + bv;
      }
    }
  }
}

// ------- gather (fp8 t): h = bf16(elu(deg_inv * sum t[src] + r)) -----------
// Slot-ordered (degree-sorted within bucket): 8 lanes/node, uint2/lane =
// 8 fp8 feats, 32 nodes/block; colidx prefetch pipeline; meta int4 one load.
// X/r addressed by node id (full-line rows, scatter is free).

__global__ __launch_bounds__(256) void gather_fp8(const uint2* __restrict__ t,
                                                  const unsigned short* __restrict__ r,
                                                  const int4* __restrict__ metaS,
                                                  const int* __restrict__ colidx,
                                                  unsigned short* __restrict__ Xout,
                                                  int N) {
  const int slot = blockIdx.x * 32 + ((int)threadIdx.x >> 3);
  const int lane = threadIdx.x & 7;
  const int4 mt = metaS[slot];
  const int node = mt.z;
  if (node >= N) return;
  const int b = mt.x;
  const int pc = mt.y & 0xFFFF;
  const int vr = mt.y >> 16;
  const int e = b + pc;                        // padded, multiple of 4
  float s[8];
#pragma unroll
  for (int k = 0; k < 8; ++k) s[k] = 0.f;
  int i = b;
  // prefetched colidx (may overrun segment by <=32B into valid ws memory)
  i32x4 c0 = __builtin_nontemporal_load((const i32x4*)&colidx[i]);
  i32x4 c1 = __builtin_nontemporal_load((const i32x4*)&colidx[i + 4]);
  for (; i + 8 <= e;) {
    i32x4 p0 = c0, p1 = c1;
    i += 8;
    c0 = __builtin_nontemporal_load((const i32x4*)&colidx[i]);
    c1 = __builtin_nontemporal_load((const i32x4*)&colidx[i + 4]);
    uint2 v[8];
    v[0] = t[(size_t)p0.x * 8 + lane];
    v[1] = t[(size_t)p0.y * 8 + lane];
    v[2] = t[(size_t)p0.z * 8 + lane];
    v[3] = t[(size_t)p0.w * 8 + lane];
    v[4] = t[(size_t)p1.x * 8 + lane];
    v[5] = t[(size_t)p1.y * 8 + lane];
    v[6] = t[(size_t)p1.z * 8 + lane];
    v[7] = t[(size_t)p1.w * 8 + lane];
#pragma unroll
    for (int j = 0; j < 8; ++j) {
      f32x2 p0f = __builtin_amdgcn_cvt_pk_f32_fp8((int)v[j].x, false);
      f32x2 p1f = __builtin_amdgcn_cvt_pk_f32_fp8((int)v[j].x, true);
      f32x2 p2f = __builtin_amdgcn_cvt_pk_f32_fp8((int)v[j].y, false);
      f32x2 p3f = __builtin_amdgcn_cvt_pk_f32_fp8((int)v[j].y, true);
      s[0] += p0f[0]; s[1] += p0f[1]; s[2] += p1f[0]; s[3] += p1f[1];
      s[4] += p2f[0]; s[5] += p2f[1]; s[6] += p3f[0]; s[7] += p3f[1];
    }
  }
  if (i < e) {                                 // exactly 4 remain (in c0)
    uint2 v[4];
    v[0] = t[(size_t)c0.x * 8 + lane];
    v[1] = t[(size_t)c0.y * 8 + lane];
    v[2] = t[(size_t)c0.z * 8 + lane];
    v[3] = t[(size_t)c0.w * 8 + lane];
#pragma unroll
    for (int j = 0; j < 4; ++j) {
      f32x2 p0f = __builtin_amdgcn_cvt_pk_f32_fp8((int)v[j].x, false);
      f32x2 p1f = __builtin_amdgcn_cvt_pk_f32_fp8((int)v[j].x, true);
      f32x2 p2f = __builtin_amdgcn_cvt_pk_f32_fp8((int)v[j].y, false);
      f32x2 p3f = __builtin_amdgcn_cvt_pk_f32_fp8((int)v[j].y, true);
      s[0] += p0f[0]; s[1] += p0f[1]; s[2] += p1f[0]; s[3] += p1f[1];
      s[4] += p2f[0]; s[5] += p2f[1]; s[6] += p3f[0]; s[7] += p3f[1];
    }
  }
  const float dv = 1.0f / (float)(vr > 1 ? vr : 1);
  const s16x8 rv = *(const s16x8*)&r[(size_t)node * 64 + lane * 8];
  s16x8 hv;
#pragma unroll
  for (int k = 0; k < 8; ++k) {
    float ak = s[k] * dv + bf2f((unsigned short)rv[k]);
    ak = ak > 0.f ? ak : (expf(ak) - 1.f);
    hv[k] = (short)f2bf(ak);
  }
  *(s16x8*)&Xout[(size_t)node * 64 + lane * 8] = hv;
}

// ------- final gather: out = deg_inv * sum t2[src] + r[dst], t2 bf16 -------

__global__ __launch_bounds__(256) void gather_out(const uint2* __restrict__ t,
                                                  const float* __restrict__ r,
                                                  const int4* __restrict__ metaS,
                                                  const int* __restrict__ colidx,
                                                  float* __restrict__ out, int N) {
  const int slot = blockIdx.x * 32 + ((int)threadIdx.x >> 3);
  const int lane = threadIdx.x & 7;
  const int4 mt = metaS[slot];
  const int node = mt.z;
  if (node >= N) return;
  const int b = mt.x;
  const int pc = mt.y & 0xFFFF;
  const int vr = mt.y >> 16;
  const int e = b + pc;                // padded, multiple of 4
  float s0 = 0.f, s1 = 0.f, s2 = 0.f, s3 = 0.f;
  int i = b;
  i32x4 c0 = __builtin_nontemporal_load((const i32x4*)&colidx[i]);
  i32x4 c1 = __builtin_nontemporal_load((const i32x4*)&colidx[i + 4]);
  for (; i + 8 <= e;) {
    i32x4 p0 = c0, p1 = c1;
    i += 8;
    c0 = __builtin_nontemporal_load((const i32x4*)&colidx[i]);
    c1 = __builtin_nontemporal_load((const i32x4*)&colidx[i + 4]);
    uint2 v[8];
    v[0] = t[(size_t)p0.x * 8 + lane];
    v[1] = t[(size_t)p0.y * 8 + lane];
    v[2] = t[(size_t)p0.z * 8 + lane];
    v[3] = t[(size_t)p0.w * 8 + lane];
    v[4] = t[(size_t)p1.x * 8 + lane];
    v[5] = t[(size_t)p1.y * 8 + lane];
    v[6] = t[(size_t)p1.z * 8 + lane];
    v[7] = t[(size_t)p1.w * 8 + lane];
#pragma unroll
    for (int j = 0; j < 8; ++j) {
      s0 += bf2f((unsigned short)(v[j].x & 0xFFFFu));
      s1 += bf2f((unsigned short)(v[j].x >> 16));
      s2 += bf2f((unsigned short)(v[j].y & 0xFFFFu));
      s3 += bf2f((unsigned short)(v[j].y >> 16));
    }
  }
  if (i < e) {                          // exactly 4 remain (in c0)
    uint2 v[4];
    v[0] = t[(size_t)c0.x * 8 + lane];
    v[1] = t[(size_t)c0.y * 8 + lane];
    v[2] = t[(size_t)c0.z * 8 + lane];
    v[3] = t[(size_t)c0.w * 8 + lane];
#pragma unroll
    for (int j = 0; j < 4; ++j) {
      s0 += bf2f((unsigned short)(v[j].x & 0xFFFFu));
      s1 += bf2f((unsigned short)(v[j].x >> 16));
      s2 += bf2f((unsigned short)(v[j].y & 0xFFFFu));
      s3 += bf2f((unsigned short)(v[j].y >> 16));
    }
  }
  const float dv = 1.0f / (float)(vr > 1 ? vr : 1);
  float4 rv = *(const float4*)&r[(size_t)node * 32 + 4 * lane];
  *(float4*)&out[(size_t)node * 32 + 4 * lane] =
      make_float4(s0 * dv + rv.x, s1 * dv + rv.y, s2 * dv + rv.z, s3 * dv + rv.w);
}

// ---------------- launch ----------------

extern "C" void kernel_launch(void* const* d_in, const int* in_sizes, int n_in,
                              void* d_out, int out_size, void* d_ws, size_t ws_size,
                              hipStream_t stream) {
  const float* x   = (const float*)d_in[0];
  const int*   ei  = (const int*)d_in[1];
  const float* Wl0 = (const float*)d_in[2];
  const float* Wr0 = (const float*)d_in[3];
  const float* b0  = (const float*)d_in[4];
  const float* Wl1 = (const float*)d_in[5];
  const float* Wr1 = (const float*)d_in[6];
  const float* b1  = (const float*)d_in[7];
  const float* Wl2 = (const float*)d_in[8];
  const float* Wr2 = (const float*)d_in[9];
  const float* b2  = (const float*)d_in[10];
  float* out = (float*)d_out;

  const int N = in_sizes[0] / 64;   // 100000
  const int E = in_sizes[1] / 2;    // 1600000
  const int* srcv = ei;
  const int* dstv = ei + E;
  const int NSB = (N + SBW - 1) >> LOGSBW;   // 391
  const int SLOTS = NSB * SBW;               // 100096

  auto al = [](size_t v) { return (v + 255) & ~(size_t)255; };
  char* w = (char*)d_ws;
  size_t oBcur = 0;
  size_t oMeta = oBcur + al(4 * (size_t)NSB);
  size_t oWsw  = oMeta + al(16 * (size_t)SLOTS);
  size_t oBin  = oWsw + al(2 * 20480);
  size_t oCol  = oBin + al(4 * (size_t)NSB * CAPS);
  size_t oP8   = oCol + al(4 * (size_t)NSB * CAPSP);
  size_t oP16  = oP8 + al((size_t)(N + 1) * 64);   // fp8 t0/t1 (+sentinel row)
  size_t oX    = oP16 + al((size_t)(N + 1) * 64);  // bf16 t2 (+sentinel row)
  size_t oR    = oX + al(2 * (size_t)N * 64);      // bf16 h buffer
  // total = oR + 2*N*64  (~57 MiB); r buffer: bf16 [N][64] or fp32 [N][32]

  int*            bcur     = (int*)(w + oBcur);
  int4*           metaS    = (int4*)(w + oMeta);
  unsigned short* Wsw      = (unsigned short*)(w + oWsw); // swizzled weights
  unsigned*       coarse   = (unsigned*)(w + oBin);
  int*            colidx   = (int*)(w + oCol);
  unsigned char*  P8       = (unsigned char*)(w + oP8);   // fp8 t0/t1
  unsigned short* P16      = (unsigned short*)(w + oP16); // bf16 t2
  unsigned short* X        = (unsigned short*)(w + oX);   // bf16 h
  unsigned short* Rb       = (unsigned short*)(w + oR);   // bf16 r (L0/L1)
  float*          Rf       = (float*)(w + oR);            // fp32 r (L2)

  int bbl = (E + CHK - 1) / CHK;   // 782
  int gb = (N + 63) / 64;          // 1563
  int ggb = SLOTS / 32;            // 3128 (32 slots/block, 8 lanes/node)

  zero_bcur<<<1, 256, 0, stream>>>(bcur, NSB);
  bin_stage<<<bbl + 40, 256, 0, stream>>>(srcv, dstv, bcur, coarse, NSB, E,
                                          Wl0, Wr0, Wl1, Wr1, Wl2, Wr2, Wsw);
  // CSR+sort (blocks [0,NSB)) overlapped with layer-0 GEMM (blocks [NSB,..))
  csr_gemm0<<<NSB + gb, 256, 0, stream>>>(coarse, bcur, metaS, colidx, x, Wsw,
                                          b0, P8, Rb, N, NSB);
  gather_fp8<<<ggb, 256, 0, stream>>>((const uint2*)P8, Rb, metaS, colidx, X, N);
  // layer 1: X -> t1 (fp8 P8), r1 (bf16 Rb)
  gemm_mfma<64, true, true><<<gb, 256, 0, stream>>>(X, Wsw + 8192, b1, P8, Rb, N);
  gather_fp8<<<ggb, 256, 0, stream>>>((const uint2*)P8, Rb, metaS, colidx, X, N);
  // layer 2: X -> t2 (bf16 P16), r2 (fp32 Rf, [N][32])
  gemm_mfma<32, false, false><<<gb, 256, 0, stream>>>(X, Wsw + 16384, b2, P16, Rf, N);
  gather_out<<<ggb, 256, 0, stream>>>((const uint2*)P16, Rf, metaS, colidx, out, N);
}

// Round 6
// 241.766 us; speedup vs baseline: 1.1513x; 1.1513x over previous
//
#include <hip/hip_runtime.h>
#include <cstdint>
#include <cstddef>

// GraphSAGE 3-layer, N=100000 nodes, E=1600000 edges, dims 64->64->64->32.
// Transform-then-aggregate; padded CSR via 256-node super-buckets;
// weights pre-swizzled once into MFMA B-frag layout (init_ws kernel);
// per-layer dual GEMMs (t=h@Wl, r=h@Wr+b, mfma_f32_16x16x32_bf16) LDS-free,
// barrier-free; t for layers 0/1 fp8 e4m3 (row=64B=1 line), t2 bf16;
// r bf16 L0/L1, fp32 L2.
// R18: STRICT revert to R14 (best, 242.7) + ONE lever: 2-stage software
//      pipeline in both gathers (issue next 8 t-loads + colidx before
//      consuming current 8) -> per-wave in-flight 8->16. VGPR ~70 halves
//      the occupancy CAP but measured occ was 54% (~4.3 waves/SIMD)
//      anyway -> net in-flight ~x1.9.
// R17: degree-sort REGRESSED (+35 vs R14): scattered r/X/out rows by node
//      id cost >> imbalance win. Node-ordered dense access is sacred.
// R16: 4-lane gather REGRESSED (+12): wave count is the MLP lever.
// R15: half-tables + 2-pass REGRESSED (+49): gathers latency-bound
//      (22% BW, 22% VALU, 54% occ); traffic is not the limit.
// R14: csr+gemm0 merged; pad-4 CSR. -12us (boundary ~3.5us each).
// R13: pad-8 sentinel CSR; r bf16 L0/L1. gathers NOT divergence-bound.
// R4: LDS-atomic aggregation is 12x slower than CSR gather — don't revisit.
// R6: per-node scatter -> 64B-line write amplification, keep super-buckets.
// R10: gather+GEMM fusion halves occupancy, couples imbalance — keep split.
// R12: R11's "slow GEMM" was broken weight staging; fp8 gather is the win.

constexpr int SBW = 256;     // dst nodes per super-bucket
constexpr int LOGSBW = 8;
constexpr int CAPS = 4608;   // super capacity (unpadded); mean 4096, +8 sigma
constexpr int CAPSP = 5632;  // padded capacity; mean ~4608 (pad-4), %16==0
constexpr int CHK = 2048;    // edges per bin block -> 782 blocks

typedef __attribute__((ext_vector_type(8))) short s16x8;
typedef __attribute__((ext_vector_type(4))) float f32x4;
typedef __attribute__((ext_vector_type(2))) float f32x2;
typedef __attribute__((ext_vector_type(4))) int i32x4;

__device__ inline unsigned short f2bf(float f) {
  unsigned u = __builtin_bit_cast(unsigned, f);
  u += 0x7FFFu + ((u >> 16) & 1u);          // round-to-nearest-even
  return (unsigned short)(u >> 16);
}
__device__ inline float bf2f(unsigned short b) {
  unsigned u = ((unsigned)b) << 16;
  return __builtin_bit_cast(float, u);
}
__device__ inline unsigned char f2fp8(float f) {
  int p = __builtin_amdgcn_cvt_pk_fp8_f32(f, f, 0, false);
  return (unsigned char)(p & 0xFF);
}

// ------- init: zero bcur (block 0) + weight swizzle (blocks 1..40) ---------
// Swizzle: per layer 2*NTT tiles (Wl then Wr); per tile 2 planes (k<32,
// k>=32); per plane 64 lanes x 8 bf16: W[k=plane*32+q*8+j][col=c*16+m].
// Layer short offsets: L0=0, L1=8192, L2=16384. gemm fetch:
// frag = Wsw[off + (c*2+plane)*512 + lane*8 ..+8] (16B/lane, coalesced).

__global__ __launch_bounds__(256) void init_ws(int* __restrict__ bcur, int NSB,
                                               const float* __restrict__ Wl0,
                                               const float* __restrict__ Wr0,
                                               const float* __restrict__ Wl1,
                                               const float* __restrict__ Wr1,
                                               const float* __restrict__ Wl2,
                                               const float* __restrict__ Wr2,
                                               unsigned short* __restrict__ Wsw) {
  const int tid = threadIdx.x;
  if (blockIdx.x == 0) {
    for (int i = tid; i < NSB; i += 256) bcur[i] = 0;
    return;
  }
  int g = (blockIdx.x - 1) * 256 + tid;        // u32 index
  if (g >= 10240) return;
  int s = g * 2;                               // short index (j even)
  int layer, off;
  if (s < 8192)       { layer = 0; off = 0; }
  else if (s < 16384) { layer = 1; off = 8192; }
  else                { layer = 2; off = 16384; }
  int t = s - off;
  int D = (layer == 2) ? 32 : 64;
  int NTT = D / 16;
  int tt = t >> 10;
  int rem = t & 1023;
  int plane = rem >> 9;
  int rem2 = rem & 511;
  int lane = rem2 >> 3;
  int j = rem2 & 7;
  int q = lane >> 4, m = lane & 15;
  int k = plane * 32 + q * 8 + j;
  const float* W;
  int c;
  if (tt < NTT) {
    c = tt;
    W = (layer == 0) ? Wl0 : (layer == 1) ? Wl1 : Wl2;
  } else {
    c = tt - NTT;
    W = (layer == 0) ? Wr0 : (layer == 1) ? Wr1 : Wr2;
  }
  int col = c * 16 + m;
  unsigned lo = f2bf(W[k * D + col]);
  unsigned hi = f2bf(W[(k + 1) * D + col]);
  *(unsigned*)&Wsw[s] = lo | (hi << 16);
}

// ------- pass 1: coarse bin into 256-node super-buckets --------------------

__global__ __launch_bounds__(256) void bin_coarse(const int* __restrict__ src,
                                                  const int* __restrict__ dst,
                                                  int* __restrict__ bcur,
                                                  unsigned int* __restrict__ coarse,
                                                  int NSB, int E) {
  __shared__ int h[512];
  __shared__ unsigned ed[CHK];
  __shared__ short sb[CHK];
  const int tid = threadIdx.x;
  for (int i = tid; i < NSB; i += 256) h[i] = 0;
  __syncthreads();
  const int e0 = blockIdx.x * CHK;
  const int e1 = min(E, e0 + CHK);
  for (int e = e0 + tid; e < e1; e += 256) {
    int d = dst[e];
    int s = src[e];
    int b = d >> LOGSBW;
    ed[e - e0] = (unsigned)s | ((unsigned)(d & (SBW - 1)) << 17);
    sb[e - e0] = (short)b;
    atomicAdd(&h[b], 1);
  }
  __syncthreads();
  for (int i = tid; i < NSB; i += 256) {
    int c = h[i];
    h[i] = c ? (i * CAPS + atomicAdd(&bcur[i], c)) : 0;  // slot -> abs cursor
  }
  __syncthreads();
  const int n = e1 - e0;
  for (int k = tid; k < n; k += 256) {
    int b = sb[k];
    int pos = atomicAdd(&h[b], 1);
    if (pos < (b + 1) * CAPS)                 // overflow guard (never taken)
      coarse[pos] = ed[k];
  }
}

// ------- pass 2: per-super count/scan/sort -> PADDED CSR, merged with -----
// ------- layer-0 dual GEMM (independent work, fills the idle CUs) ---------
// CSR: blocks [0,NSB). Segments padded to x4 with sentinel colidx=N (row N
// of t tables is zero) -> branch-free gather main loop + one 4-edge tail.
// GEMM0: blocks [NSB, NSB+gb): fp32 x -> t0 fp8 + r0 bf16.
// C/D layout: col=lane&15, row=(lane>>4)*4+reg (m89-verified).

__global__ __launch_bounds__(256) void csr_gemm0(const unsigned int* __restrict__ coarse,
                                                 const int* __restrict__ bcur,
                                                 int* __restrict__ rowstart,
                                                 int* __restrict__ degarr,
                                                 float* __restrict__ deg_inv,
                                                 int* __restrict__ colidx,
                                                 const float* __restrict__ x,
                                                 const unsigned short* __restrict__ Wf,
                                                 const float* __restrict__ bias,
                                                 unsigned char* __restrict__ t_out,
                                                 unsigned short* __restrict__ r_out,
                                                 int N, int NSB) {
  __shared__ int cnt[SBW];
  __shared__ int sc[SBW];
  __shared__ int cur[SBW];
  const int tid = threadIdx.x;
  if ((int)blockIdx.x < NSB) {
    // ---------------- CSR path ----------------
    const int b = blockIdx.x;
    cnt[tid] = 0;
    __syncthreads();
    const int ec = min(bcur[b], CAPS);
    const int baseC = b * CAPS;
    const int baseP = b * CAPSP;
    for (int e = tid; e < ec; e += 256)
      atomicAdd(&cnt[coarse[baseC + e] >> 17], 1);
    __syncthreads();
    int v = cnt[tid];
    int pc = (v + 3) & ~3;                      // padded count (x4)
    sc[tid] = pc;
    __syncthreads();
    for (int off = 1; off < SBW; off <<= 1) {
      int y = sc[tid];
      if (tid >= off) y += sc[tid - off];
      __syncthreads();
      sc[tid] = y;
      __syncthreads();
    }
    int pex = sc[tid] - pc;                     // exclusive padded prefix
    cur[tid] = pex;
    int gn = b * SBW + tid;
    if (gn < N) {
      rowstart[gn] = baseP + pex;
      degarr[gn] = pc;                          // padded extent for the gather
      deg_inv[gn] = 1.0f / (float)(v > 1 ? v : 1);
    }
    __syncthreads();
    for (int e = tid; e < ec; e += 256) {
      unsigned p = coarse[baseC + e];
      int dl = (int)(p >> 17);
      int s = (int)(p & 0x1FFFFu);
      int l = atomicAdd(&cur[dl], 1);
      if (l < CAPSP)                            // overflow guard (never taken)
        colidx[baseP + l] = s;
    }
    // sentinel padding (disjoint from scatter range, no sync needed)
    int pe = pex + pc;
    if (pe > CAPSP) pe = CAPSP;
    for (int l = pex + v; l < pe; ++l) colidx[baseP + l] = N;
    return;
  }
  // ---------------- GEMM0 path ----------------
  constexpr int DOUT = 64;
  constexpr int NTT = 4;
  const int gbid = blockIdx.x - NSB;
  if (gbid == 0 && tid < 16)                   // zero sentinel row N of t
    ((unsigned*)t_out)[(size_t)N * 16 + tid] = 0u;
  const int wv = tid >> 6, lane = tid & 63;
  const int q = lane >> 4, m = lane & 15;
  const int row = gbid * 64 + wv * 16 + m;
  const int rowc = row < N ? row : N - 1;
  const float* xp = &x[(size_t)rowc * 64];
  float4 f0 = *(const float4*)&xp[q * 8];
  float4 f1 = *(const float4*)&xp[q * 8 + 4];
  float4 f2 = *(const float4*)&xp[32 + q * 8];
  float4 f3 = *(const float4*)&xp[32 + q * 8 + 4];
  s16x8 a0, a1;
  a0[0] = (short)f2bf(f0.x); a0[1] = (short)f2bf(f0.y);
  a0[2] = (short)f2bf(f0.z); a0[3] = (short)f2bf(f0.w);
  a0[4] = (short)f2bf(f1.x); a0[5] = (short)f2bf(f1.y);
  a0[6] = (short)f2bf(f1.z); a0[7] = (short)f2bf(f1.w);
  a1[0] = (short)f2bf(f2.x); a1[1] = (short)f2bf(f2.y);
  a1[2] = (short)f2bf(f2.z); a1[3] = (short)f2bf(f2.w);
  a1[4] = (short)f2bf(f3.x); a1[5] = (short)f2bf(f3.y);
  a1[6] = (short)f2bf(f3.z); a1[7] = (short)f2bf(f3.w);

  f32x4 acc[2 * NTT];
#pragma unroll
  for (int c = 0; c < 2 * NTT; ++c) acc[c] = (f32x4){0.f, 0.f, 0.f, 0.f};
#pragma unroll
  for (int c = 0; c < 2 * NTT; ++c) {
    s16x8 b0 = *(const s16x8*)&Wf[(c * 2 + 0) * 512 + lane * 8];
    s16x8 b1 = *(const s16x8*)&Wf[(c * 2 + 1) * 512 + lane * 8];
    acc[c] = __builtin_amdgcn_mfma_f32_16x16x32_bf16(a0, b0, acc[c], 0, 0, 0);
    acc[c] = __builtin_amdgcn_mfma_f32_16x16x32_bf16(a1, b1, acc[c], 0, 0, 0);
  }

  const int orow = gbid * 64 + wv * 16 + q * 4;
#pragma unroll
  for (int c = 0; c < NTT; ++c) {
#pragma unroll
    for (int i = 0; i < 4; ++i) {
      int r_ = orow + i;
      if (r_ < N) t_out[(size_t)r_ * DOUT + c * 16 + m] = f2fp8(acc[c][i]);
    }
  }
#pragma unroll
  for (int c = 0; c < NTT; ++c) {
    float bv = bias[c * 16 + m];
#pragma unroll
    for (int i = 0; i < 4; ++i) {
      int r_ = orow + i;
      if (r_ < N) r_out[(size_t)r_ * 64 + c * 16 + m] = f2bf(acc[NTT + c][i] + bv);
    }
  }
}

// ------- mid/final MFMA dual GEMM, bf16 input, LDS-free --------------------
// TFP8: t out fp8 (layer 1) else bf16 (layer 2). RB16: r out bf16 else fp32.

template <int DOUT, bool TFP8, bool RB16>
__global__ __launch_bounds__(256) void gemm_mfma(const unsigned short* __restrict__ Hm,
                                                 const unsigned short* __restrict__ Wf,
                                                 const float* __restrict__ bias,
                                                 void* __restrict__ t_out,
                                                 void* __restrict__ r_out, int N) {
  constexpr int NTT = DOUT / 16;
  constexpr int ROWB = TFP8 ? DOUT : DOUT * 2;   // t row bytes (always 64 here)
  const int tid = threadIdx.x;
  if (blockIdx.x == 0 && tid < ROWB / 4)        // zero sentinel row N of t
    ((unsigned*)((char*)t_out + (size_t)N * ROWB))[tid] = 0u;
  const int wv = tid >> 6, lane = tid & 63;
  const int q = lane >> 4, m = lane & 15;
  const int row = blockIdx.x * 64 + wv * 16 + m;
  const int rowc = row < N ? row : N - 1;
  const s16x8 a0 = *(const s16x8*)&Hm[(size_t)rowc * 64 + q * 8];
  const s16x8 a1 = *(const s16x8*)&Hm[(size_t)rowc * 64 + 32 + q * 8];

  f32x4 acc[2 * NTT];
#pragma unroll
  for (int c = 0; c < 2 * NTT; ++c) acc[c] = (f32x4){0.f, 0.f, 0.f, 0.f};
#pragma unroll
  for (int c = 0; c < 2 * NTT; ++c) {
    s16x8 b0 = *(const s16x8*)&Wf[(c * 2 + 0) * 512 + lane * 8];
    s16x8 b1 = *(const s16x8*)&Wf[(c * 2 + 1) * 512 + lane * 8];
    acc[c] = __builtin_amdgcn_mfma_f32_16x16x32_bf16(a0, b0, acc[c], 0, 0, 0);
    acc[c] = __builtin_amdgcn_mfma_f32_16x16x32_bf16(a1, b1, acc[c], 0, 0, 0);
  }

  const int orow = blockIdx.x * 64 + wv * 16 + q * 4;
#pragma unroll
  for (int c = 0; c < NTT; ++c) {
#pragma unroll
    for (int i = 0; i < 4; ++i) {
      int r_ = orow + i;
      if (r_ < N) {
        if (TFP8)
          ((unsigned char*)t_out)[(size_t)r_ * DOUT + c * 16 + m] = f2fp8(acc[c][i]);
        else
          ((unsigned short*)t_out)[(size_t)r_ * DOUT + c * 16 + m] = f2bf(acc[c][i]);
      }
    }
  }
#pragma unroll
  for (int c = 0; c < NTT; ++c) {
    float bv = bias[c * 16 + m];
#pragma unroll
    for (int i = 0; i < 4; ++i) {
      int r_ = orow + i;
      if (r_ < N) {
        if (RB16)
          ((unsigned short*)r_out)[(size_t)r_ * DOUT + c * 16 + m] =
              f2bf(acc[NTT + c][i] + bv);
        else
          ((float*)r_out)[(size_t)r_ * DOUT + c * 16 + m] = acc[NTT + c][i] + bv;
      }
    }
  }
}

// ------- gather (fp8 t): h = bf16(elu(deg_inv * sum t[src] + r)) -----------
// 8 lanes/node, uint2/lane = 8 fp8 feats; row = 64B = 1 line. 2-stage
// software pipeline: next 8 colidx+t loads issued BEFORE consuming current
// 8 -> 16 loads in flight per wave. Segments padded to x4; 4-edge tail.

__global__ __launch_bounds__(256) void gather_fp8(const uint2* __restrict__ t,
                                                  const unsigned short* __restrict__ r,
                                                  const float* __restrict__ deg_inv,
                                                  const int* __restrict__ rowstart,
                                                  const int* __restrict__ degarr,
                                                  const int* __restrict__ colidx,
                                                  unsigned short* __restrict__ Xout,
                                                  int N) {
  int node = blockIdx.x * 32 + (threadIdx.x >> 3);
  int lane = threadIdx.x & 7;
  if (node >= N) return;
  int b = rowstart[node];
  int e = b + degarr[node];                    // padded, multiple of 4
  float s[8];
#pragma unroll
  for (int k = 0; k < 8; ++k) s[k] = 0.f;
  int i = b;
  if (i + 8 <= e) {
    i32x4 c0 = *(const i32x4*)&colidx[i];
    i32x4 c1 = *(const i32x4*)&colidx[i + 4];
    uint2 va[8];
    va[0] = t[(size_t)c0.x * 8 + lane];
    va[1] = t[(size_t)c0.y * 8 + lane];
    va[2] = t[(size_t)c0.z * 8 + lane];
    va[3] = t[(size_t)c0.w * 8 + lane];
    va[4] = t[(size_t)c1.x * 8 + lane];
    va[5] = t[(size_t)c1.y * 8 + lane];
    va[6] = t[(size_t)c1.z * 8 + lane];
    va[7] = t[(size_t)c1.w * 8 + lane];
    while (i + 16 <= e) {
      i32x4 n0 = *(const i32x4*)&colidx[i + 8];
      i32x4 n1 = *(const i32x4*)&colidx[i + 12];
      uint2 vb[8];
      vb[0] = t[(size_t)n0.x * 8 + lane];
      vb[1] = t[(size_t)n0.y * 8 + lane];
      vb[2] = t[(size_t)n0.z * 8 + lane];
      vb[3] = t[(size_t)n0.w * 8 + lane];
      vb[4] = t[(size_t)n1.x * 8 + lane];
      vb[5] = t[(size_t)n1.y * 8 + lane];
      vb[6] = t[(size_t)n1.z * 8 + lane];
      vb[7] = t[(size_t)n1.w * 8 + lane];
#pragma unroll
      for (int j = 0; j < 8; ++j) {
        f32x2 p0 = __builtin_amdgcn_cvt_pk_f32_fp8((int)va[j].x, false);
        f32x2 p1 = __builtin_amdgcn_cvt_pk_f32_fp8((int)va[j].x, true);
        f32x2 p2 = __builtin_amdgcn_cvt_pk_f32_fp8((int)va[j].y, false);
        f32x2 p3 = __builtin_amdgcn_cvt_pk_f32_fp8((int)va[j].y, true);
        s[0] += p0[0]; s[1] += p0[1]; s[2] += p1[0]; s[3] += p1[1];
        s[4] += p2[0]; s[5] += p2[1]; s[6] += p3[0]; s[7] += p3[1];
      }
#pragma unroll
      for (int j = 0; j < 8; ++j) va[j] = vb[j];
      i += 8;
    }
#pragma unroll
    for (int j = 0; j < 8; ++j) {
      f32x2 p0 = __builtin_amdgcn_cvt_pk_f32_fp8((int)va[j].x, false);
      f32x2 p1 = __builtin_amdgcn_cvt_pk_f32_fp8((int)va[j].x, true);
      f32x2 p2 = __builtin_amdgcn_cvt_pk_f32_fp8((int)va[j].y, false);
      f32x2 p3 = __builtin_amdgcn_cvt_pk_f32_fp8((int)va[j].y, true);
      s[0] += p0[0]; s[1] += p0[1]; s[2] += p1[0]; s[3] += p1[1];
      s[4] += p2[0]; s[5] += p2[1]; s[6] += p3[0]; s[7] += p3[1];
    }
    i += 8;
  }
  if (i < e) {                                 // exactly 4 remain
    i32x4 c0 = *(const i32x4*)&colidx[i];
    uint2 v[4];
    v[0] = t[(size_t)c0.x * 8 + lane];
    v[1] = t[(size_t)c0.y * 8 + lane];
    v[2] = t[(size_t)c0.z * 8 + lane];
    v[3] = t[(size_t)c0.w * 8 + lane];
#pragma unroll
    for (int j = 0; j < 4; ++j) {
      f32x2 p0 = __builtin_amdgcn_cvt_pk_f32_fp8((int)v[j].x, false);
      f32x2 p1 = __builtin_amdgcn_cvt_pk_f32_fp8((int)v[j].x, true);
      f32x2 p2 = __builtin_amdgcn_cvt_pk_f32_fp8((int)v[j].y, false);
      f32x2 p3 = __builtin_amdgcn_cvt_pk_f32_fp8((int)v[j].y, true);
      s[0] += p0[0]; s[1] += p0[1]; s[2] += p1[0]; s[3] += p1[1];
      s[4] += p2[0]; s[5] += p2[1]; s[6] += p3[0]; s[7] += p3[1];
    }
  }
  float dv = deg_inv[node];
  const s16x8 rv = *(const s16x8*)&r[(size_t)node * 64 + lane * 8];
  s16x8 hv;
#pragma unroll
  for (int k = 0; k < 8; ++k) {
    float ak = s[k] * dv + bf2f((unsigned short)rv[k]);
    ak = ak > 0.f ? ak : (expf(ak) - 1.f);
    hv[k] = (short)f2bf(ak);
  }
  *(s16x8*)&Xout[(size_t)node * 64 + lane * 8] = hv;
}

// ------- final gather: out = deg_inv * sum t2[src] + r[dst], t2 bf16 -------
// Same 2-stage pipeline; 8 lanes/node, uint2 = 4 bf16 per lane.

__global__ __launch_bounds__(256) void gather_out(const uint2* __restrict__ t,
                                                  const float* __restrict__ r,
                                                  const float* __restrict__ deg_inv,
                                                  const int* __restrict__ rowstart,
                                                  const int* __restrict__ degarr,
                                                  const int* __restrict__ colidx,
                                                  float* __restrict__ out, int N) {
  int node = blockIdx.x * 32 + (threadIdx.x >> 3);
  int lane = threadIdx.x & 7;
  if (node >= N) return;
  int b = rowstart[node];
  int e = b + degarr[node];            // padded, multiple of 4
  float s0 = 0.f, s1 = 0.f, s2 = 0.f, s3 = 0.f;
  int i = b;
  if (i + 8 <= e) {
    i32x4 c0 = *(const i32x4*)&colidx[i];
    i32x4 c1 = *(const i32x4*)&colidx[i + 4];
    uint2 va[8];
    va[0] = t[(size_t)c0.x * 8 + lane];
    va[1] = t[(size_t)c0.y * 8 + lane];
    va[2] = t[(size_t)c0.z * 8 + lane];
    va[3] = t[(size_t)c0.w * 8 + lane];
    va[4] = t[(size_t)c1.x * 8 + lane];
    va[5] = t[(size_t)c1.y * 8 + lane];
    va[6] = t[(size_t)c1.z * 8 + lane];
    va[7] = t[(size_t)c1.w * 8 + lane];
    while (i + 16 <= e) {
      i32x4 n0 = *(const i32x4*)&colidx[i + 8];
      i32x4 n1 = *(const i32x4*)&colidx[i + 12];
      uint2 vb[8];
      vb[0] = t[(size_t)n0.x * 8 + lane];
      vb[1] = t[(size_t)n0.y * 8 + lane];
      vb[2] = t[(size_t)n0.z * 8 + lane];
      vb[3] = t[(size_t)n0.w * 8 + lane];
      vb[4] = t[(size_t)n1.x * 8 + lane];
      vb[5] = t[(size_t)n1.y * 8 + lane];
      vb[6] = t[(size_t)n1.z * 8 + lane];
      vb[7] = t[(size_t)n1.w * 8 + lane];
#pragma unroll
      for (int j = 0; j < 8; ++j) {
        s0 += bf2f((unsigned short)(va[j].x & 0xFFFFu));
        s1 += bf2f((unsigned short)(va[j].x >> 16));
        s2 += bf2f((unsigned short)(va[j].y & 0xFFFFu));
        s3 += bf2f((unsigned short)(va[j].y >> 16));
      }
#pragma unroll
      for (int j = 0; j < 8; ++j) va[j] = vb[j];
      i += 8;
    }
#pragma unroll
    for (int j = 0; j < 8; ++j) {
      s0 += bf2f((unsigned short)(va[j].x & 0xFFFFu));
      s1 += bf2f((unsigned short)(va[j].x >> 16));
      s2 += bf2f((unsigned short)(va[j].y & 0xFFFFu));
      s3 += bf2f((unsigned short)(va[j].y >> 16));
    }
    i += 8;
  }
  if (i < e) {                          // exactly 4 remain
    i32x4 c0 = *(const i32x4*)&colidx[i];
    uint2 v[4];
    v[0] = t[(size_t)c0.x * 8 + lane];
    v[1] = t[(size_t)c0.y * 8 + lane];
    v[2] = t[(size_t)c0.z * 8 + lane];
    v[3] = t[(size_t)c0.w * 8 + lane];
#pragma unroll
    for (int j = 0; j < 4; ++j) {
      s0 += bf2f((unsigned short)(v[j].x & 0xFFFFu));
      s1 += bf2f((unsigned short)(v[j].x >> 16));
      s2 += bf2f((unsigned short)(v[j].y & 0xFFFFu));
      s3 += bf2f((unsigned short)(v[j].y >> 16));
    }
  }
  float dv = deg_inv[node];
  float4 rv = *(const float4*)&r[(size_t)node * 32 + 4 * lane];
  *(float4*)&out[(size_t)node * 32 + 4 * lane] =
      make_float4(s0 * dv + rv.x, s1 * dv + rv.y, s2 * dv + rv.z, s3 * dv + rv.w);
}

// ---------------- launch ----------------

extern "C" void kernel_launch(void* const* d_in, const int* in_sizes, int n_in,
                              void* d_out, int out_size, void* d_ws, size_t ws_size,
                              hipStream_t stream) {
  const float* x   = (const float*)d_in[0];
  const int*   ei  = (const int*)d_in[1];
  const float* Wl0 = (const float*)d_in[2];
  const float* Wr0 = (const float*)d_in[3];
  const float* b0  = (const float*)d_in[4];
  const float* Wl1 = (const float*)d_in[5];
  const float* Wr1 = (const float*)d_in[6];
  const float* b1  = (const float*)d_in[7];
  const float* Wl2 = (const float*)d_in[8];
  const float* Wr2 = (const float*)d_in[9];
  const float* b2  = (const float*)d_in[10];
  float* out = (float*)d_out;

  const int N = in_sizes[0] / 64;   // 100000
  const int E = in_sizes[1] / 2;    // 1600000
  const int* srcv = ei;
  const int* dstv = ei + E;
  const int NSB = (N + SBW - 1) >> LOGSBW;   // 391

  auto al = [](size_t v) { return (v + 255) & ~(size_t)255; };
  char* w = (char*)d_ws;
  size_t oBcur = 0;
  size_t oRow  = oBcur + al(4 * (size_t)NSB);
  size_t oDeg  = oRow + al(4 * (size_t)N);
  size_t oDinv = oDeg + al(4 * (size_t)N);
  size_t oWsw  = oDinv + al(4 * (size_t)N);
  size_t oBin  = oWsw + al(2 * 20480);
  size_t oCol  = oBin + al(4 * (size_t)NSB * CAPS);
  size_t oP8   = oCol + al(4 * (size_t)NSB * CAPSP);
  size_t oP16  = oP8 + al((size_t)(N + 1) * 64);   // fp8 t0/t1 (+sentinel row)
  size_t oX    = oP16 + al((size_t)(N + 1) * 64);  // bf16 t2 (+sentinel row)
  size_t oR    = oX + al(2 * (size_t)N * 64);      // bf16 h buffer
  // total = oR + 2*N*64  (~55 MiB); r buffer: bf16 [N][64] or fp32 [N][32]

  int*            bcur     = (int*)(w + oBcur);
  int*            rowstart = (int*)(w + oRow);
  int*            degarr   = (int*)(w + oDeg);
  float*          deg_inv  = (float*)(w + oDinv);
  unsigned short* Wsw      = (unsigned short*)(w + oWsw); // swizzled weights
  unsigned*       coarse   = (unsigned*)(w + oBin);
  int*            colidx   = (int*)(w + oCol);
  unsigned char*  P8       = (unsigned char*)(w + oP8);   // fp8 t0/t1
  unsigned short* P16      = (unsigned short*)(w + oP16); // bf16 t2
  unsigned short* X        = (unsigned short*)(w + oX);   // bf16 h
  unsigned short* Rb       = (unsigned short*)(w + oR);   // bf16 r (L0/L1)
  float*          Rf       = (float*)(w + oR);            // fp32 r (L2)

  int bbl = (E + CHK - 1) / CHK;   // 782
  int gb = (N + 63) / 64;          // 1563
  int ggb = (N + 31) / 32;         // 3125

  init_ws<<<41, 256, 0, stream>>>(bcur, NSB, Wl0, Wr0, Wl1, Wr1, Wl2, Wr2, Wsw);
  bin_coarse<<<bbl, 256, 0, stream>>>(srcv, dstv, bcur, coarse, NSB, E);
  // CSR build (blocks [0,NSB)) overlapped with layer-0 GEMM (blocks [NSB,..))
  csr_gemm0<<<NSB + gb, 256, 0, stream>>>(coarse, bcur, rowstart, degarr,
                                          deg_inv, colidx, x, Wsw, b0, P8, Rb,
                                          N, NSB);
  gather_fp8<<<ggb, 256, 0, stream>>>((const uint2*)P8, Rb, deg_inv, rowstart,
                                      degarr, colidx, X, N);
  // layer 1: X -> t1 (fp8 P8), r1 (bf16 Rb)
  gemm_mfma<64, true, true><<<gb, 256, 0, stream>>>(X, Wsw + 8192, b1, P8, Rb, N);
  gather_fp8<<<ggb, 256, 0, stream>>>((const uint2*)P8, Rb, deg_inv, rowstart,
                                      degarr, colidx, X, N);
  // layer 2: X -> t2 (bf16 P16), r2 (fp32 Rf, [N][32])
  gemm_mfma<32, false, false><<<gb, 256, 0, stream>>>(X, Wsw + 16384, b2, P16, Rf, N);
  gather_out<<<ggb, 256, 0, stream>>>((const uint2*)P16, Rf, deg_inv, rowstart,
                                      degarr, colidx, out, N);
}

// Round 7
// 241.628 us; speedup vs baseline: 1.1519x; 1.0006x over previous
//
#include <hip/hip_runtime.h>
#include <cstdint>
#include <cstddef>

// GraphSAGE 3-layer, N=100000 nodes, E=1600000 edges, dims 64->64->64->32.
// Transform-then-aggregate; padded CSR via 256-node super-buckets;
// weights pre-swizzled once into MFMA B-frag layout (bin tail blocks);
// per-layer dual GEMMs (t=h@Wl, r=h@Wr+b, mfma_f32_16x16x32_bf16) LDS-free,
// barrier-free; t for layers 0/1 fp8 e4m3 (row=64B=1 line), t2 bf16;
// r bf16 L0/L1, fp32 L2.
// R19: streaming bundle (gathers structurally at their latency floor):
//      register-staged bin (no ed/sb LDS passes), swizzle in bin tail +
//      memset for bcur (init_ws kernel removed), packed int2 meta
//      (rowstart, pc|deg<<16) in gathers (3 node-loads -> 1).
// R18: 2-stage gather pipeline NEUTRAL -> per-wave MLP not the limit; with
//      R15/R16 this pins the gathers at per-CU outstanding-miss capacity
//      vs L3 latency (structural). ~115-125us for 3 gathers is the floor.
// R17: degree-sort REGRESSED (+35): scattered r/X/out node rows cost >>
//      imbalance win. Node-ordered dense access is sacred.
// R16: 4-lane gather REGRESSED (+12): wave count is the MLP lever.
// R15: half-tables + 2-pass REGRESSED (+49): traffic is not the limit;
//      32B rows over-fetch lines.
// R14: csr+gemm0 merged; pad-4 CSR. Boundary ~3.5us each.
// R4: LDS-atomic aggregation is 12x slower than CSR gather — don't revisit.
// R6: per-node scatter -> 64B-line write amplification, keep super-buckets.
// R10: gather+GEMM fusion halves occupancy, couples imbalance — keep split.
// R12: R11's "slow GEMM" was broken weight staging; fp8 gather is the win.

constexpr int SBW = 256;     // dst nodes per super-bucket
constexpr int LOGSBW = 8;
constexpr int CAPS = 4608;   // super capacity (unpadded); mean 4096, +8 sigma
constexpr int CAPSP = 5632;  // padded capacity; mean ~4608 (pad-4), %16==0
constexpr int CHK = 2048;    // edges per bin block -> 782 blocks

typedef __attribute__((ext_vector_type(8))) short s16x8;
typedef __attribute__((ext_vector_type(4))) float f32x4;
typedef __attribute__((ext_vector_type(2))) float f32x2;
typedef __attribute__((ext_vector_type(4))) int i32x4;

__device__ inline unsigned short f2bf(float f) {
  unsigned u = __builtin_bit_cast(unsigned, f);
  u += 0x7FFFu + ((u >> 16) & 1u);          // round-to-nearest-even
  return (unsigned short)(u >> 16);
}
__device__ inline float bf2f(unsigned short b) {
  unsigned u = ((unsigned)b) << 16;
  return __builtin_bit_cast(float, u);
}
__device__ inline unsigned char f2fp8(float f) {
  int p = __builtin_amdgcn_cvt_pk_fp8_f32(f, f, 0, false);
  return (unsigned char)(p & 0xFF);
}

// ------- pass 1: coarse bin (blocks [0,bbl), register-staged) + -----------
// ------- weight swizzle tail (blocks [bbl,bbl+40)) ------------------------
// Swizzle: per layer 2*NTT tiles (Wl then Wr); per tile 2 planes (k<32,
// k>=32); per plane 64 lanes x 8 bf16: W[k=plane*32+q*8+j][col=c*16+m].
// Layer short offsets: L0=0, L1=8192, L2=16384. gemm fetch:
// frag = Wsw[off + (c*2+plane)*512 + lane*8 ..+8] (16B/lane, coalesced).

__global__ __launch_bounds__(256) void bin_stage(const int* __restrict__ src,
                                                 const int* __restrict__ dst,
                                                 int* __restrict__ bcur,
                                                 unsigned int* __restrict__ coarse,
                                                 int NSB, int E,
                                                 const float* __restrict__ Wl0,
                                                 const float* __restrict__ Wr0,
                                                 const float* __restrict__ Wl1,
                                                 const float* __restrict__ Wr1,
                                                 const float* __restrict__ Wl2,
                                                 const float* __restrict__ Wr2,
                                                 unsigned short* __restrict__ Wsw) {
  __shared__ int h[512];
  const int tid = threadIdx.x;
  const int bbl = (E + CHK - 1) / CHK;
  if ((int)blockIdx.x >= bbl) {
    // ---- weight swizzle path ----
    int g = (blockIdx.x - bbl) * 256 + tid;    // u32 index
    if (g >= 10240) return;
    int s = g * 2;                             // short index (j even)
    int layer, off;
    if (s < 8192)       { layer = 0; off = 0; }
    else if (s < 16384) { layer = 1; off = 8192; }
    else                { layer = 2; off = 16384; }
    int t = s - off;
    int D = (layer == 2) ? 32 : 64;
    int NTT = D / 16;
    int tt = t >> 10;
    int rem = t & 1023;
    int plane = rem >> 9;
    int rem2 = rem & 511;
    int lane = rem2 >> 3;
    int j = rem2 & 7;
    int q = lane >> 4, m = lane & 15;
    int k = plane * 32 + q * 8 + j;
    const float* W;
    int c;
    if (tt < NTT) {
      c = tt;
      W = (layer == 0) ? Wl0 : (layer == 1) ? Wl1 : Wl2;
    } else {
      c = tt - NTT;
      W = (layer == 0) ? Wr0 : (layer == 1) ? Wr1 : Wr2;
    }
    int col = c * 16 + m;
    unsigned lo = f2bf(W[k * D + col]);
    unsigned hi = f2bf(W[(k + 1) * D + col]);
    *(unsigned*)&Wsw[s] = lo | (hi << 16);
    return;
  }
  // ---- binning path: 8 edges/thread staged in REGISTERS ----
  for (int i = tid; i < NSB; i += 256) h[i] = 0;
  __syncthreads();
  const int e0 = blockIdx.x * CHK;
  const int e1 = min(E, e0 + CHK);
  unsigned pk[8];
  int bk[8];
#pragma unroll
  for (int k = 0; k < 8; ++k) {
    int e = e0 + tid + k * 256;
    if (e < e1) {
      int d = dst[e];
      int s = src[e];
      int b = d >> LOGSBW;
      pk[k] = (unsigned)s | ((unsigned)(d & (SBW - 1)) << 17);
      bk[k] = b;
      atomicAdd(&h[b], 1);
    } else {
      bk[k] = -1;
    }
  }
  __syncthreads();
  for (int i = tid; i < NSB; i += 256) {
    int c = h[i];
    h[i] = c ? (i * CAPS + atomicAdd(&bcur[i], c)) : 0;  // slot -> abs cursor
  }
  __syncthreads();
#pragma unroll
  for (int k = 0; k < 8; ++k) {
    if (bk[k] >= 0) {
      int pos = atomicAdd(&h[bk[k]], 1);
      if (pos < (bk[k] + 1) * CAPS)           // overflow guard (never taken)
        coarse[pos] = pk[k];
    }
  }
}

// ------- pass 2: per-super count/scan/sort -> PADDED CSR + packed meta, ---
// ------- merged with layer-0 dual GEMM (fills the idle CUs) ---------------
// CSR: blocks [0,NSB). Segments padded to x4, sentinel colidx=N (t row N is
// zero). meta int2 = (rowstart, pc|deg<<16).
// GEMM0: blocks [NSB, NSB+gb): fp32 x -> t0 fp8 + r0 bf16.
// C/D layout: col=lane&15, row=(lane>>4)*4+reg (m89-verified).

__global__ __launch_bounds__(256) void csr_gemm0(const unsigned int* __restrict__ coarse,
                                                 const int* __restrict__ bcur,
                                                 int2* __restrict__ meta,
                                                 int* __restrict__ colidx,
                                                 const float* __restrict__ x,
                                                 const unsigned short* __restrict__ Wf,
                                                 const float* __restrict__ bias,
                                                 unsigned char* __restrict__ t_out,
                                                 unsigned short* __restrict__ r_out,
                                                 int N, int NSB) {
  __shared__ int cnt[SBW];
  __shared__ int sc[SBW];
  __shared__ int cur[SBW];
  const int tid = threadIdx.x;
  if ((int)blockIdx.x < NSB) {
    // ---------------- CSR path ----------------
    const int b = blockIdx.x;
    cnt[tid] = 0;
    __syncthreads();
    const int ec = min(bcur[b], CAPS);
    const int baseC = b * CAPS;
    const int baseP = b * CAPSP;
    for (int e = tid; e < ec; e += 256)
      atomicAdd(&cnt[coarse[baseC + e] >> 17], 1);
    __syncthreads();
    int v = cnt[tid];
    int pc = (v + 3) & ~3;                      // padded count (x4)
    sc[tid] = pc;
    __syncthreads();
    for (int off = 1; off < SBW; off <<= 1) {
      int y = sc[tid];
      if (tid >= off) y += sc[tid - off];
      __syncthreads();
      sc[tid] = y;
      __syncthreads();
    }
    int pex = sc[tid] - pc;                     // exclusive padded prefix
    cur[tid] = pex;
    int gn = b * SBW + tid;
    if (gn < N)
      meta[gn] = make_int2(baseP + pex, pc | (v << 16));
    __syncthreads();
    for (int e = tid; e < ec; e += 256) {
      unsigned p = coarse[baseC + e];
      int dl = (int)(p >> 17);
      int s = (int)(p & 0x1FFFFu);
      int l = atomicAdd(&cur[dl], 1);
      if (l < CAPSP)                            // overflow guard (never taken)
        colidx[baseP + l] = s;
    }
    // sentinel padding (disjoint from scatter range, no sync needed)
    int pe = pex + pc;
    if (pe > CAPSP) pe = CAPSP;
    for (int l = pex + v; l < pe; ++l) colidx[baseP + l] = N;
    return;
  }
  // ---------------- GEMM0 path ----------------
  constexpr int DOUT = 64;
  constexpr int NTT = 4;
  const int gbid = blockIdx.x - NSB;
  if (gbid == 0 && tid < 16)                   // zero sentinel row N of t
    ((unsigned*)t_out)[(size_t)N * 16 + tid] = 0u;
  const int wv = tid >> 6, lane = tid & 63;
  const int q = lane >> 4, m = lane & 15;
  const int row = gbid * 64 + wv * 16 + m;
  const int rowc = row < N ? row : N - 1;
  const float* xp = &x[(size_t)rowc * 64];
  float4 f0 = *(const float4*)&xp[q * 8];
  float4 f1 = *(const float4*)&xp[q * 8 + 4];
  float4 f2 = *(const float4*)&xp[32 + q * 8];
  float4 f3 = *(const float4*)&xp[32 + q * 8 + 4];
  s16x8 a0, a1;
  a0[0] = (short)f2bf(f0.x); a0[1] = (short)f2bf(f0.y);
  a0[2] = (short)f2bf(f0.z); a0[3] = (short)f2bf(f0.w);
  a0[4] = (short)f2bf(f1.x); a0[5] = (short)f2bf(f1.y);
  a0[6] = (short)f2bf(f1.z); a0[7] = (short)f2bf(f1.w);
  a1[0] = (short)f2bf(f2.x); a1[1] = (short)f2bf(f2.y);
  a1[2] = (short)f2bf(f2.z); a1[3] = (short)f2bf(f2.w);
  a1[4] = (short)f2bf(f3.x); a1[5] = (short)f2bf(f3.y);
  a1[6] = (short)f2bf(f3.z); a1[7] = (short)f2bf(f3.w);

  f32x4 acc[2 * NTT];
#pragma unroll
  for (int c = 0; c < 2 * NTT; ++c) acc[c] = (f32x4){0.f, 0.f, 0.f, 0.f};
#pragma unroll
  for (int c = 0; c < 2 * NTT; ++c) {
    s16x8 b0 = *(const s16x8*)&Wf[(c * 2 + 0) * 512 + lane * 8];
    s16x8 b1 = *(const s16x8*)&Wf[(c * 2 + 1) * 512 + lane * 8];
    acc[c] = __builtin_amdgcn_mfma_f32_16x16x32_bf16(a0, b0, acc[c], 0, 0, 0);
    acc[c] = __builtin_amdgcn_mfma_f32_16x16x32_bf16(a1, b1, acc[c], 0, 0, 0);
  }

  const int orow = gbid * 64 + wv * 16 + q * 4;
#pragma unroll
  for (int c = 0; c < NTT; ++c) {
#pragma unroll
    for (int i = 0; i < 4; ++i) {
      int r_ = orow + i;
      if (r_ < N) t_out[(size_t)r_ * DOUT + c * 16 + m] = f2fp8(acc[c][i]);
    }
  }
#pragma unroll
  for (int c = 0; c < NTT; ++c) {
    float bv = bias[c * 16 + m];
#pragma unroll
    for (int i = 0; i < 4; ++i) {
      int r_ = orow + i;
      if (r_ < N) r_out[(size_t)r_ * 64 + c * 16 + m] = f2bf(acc[NTT + c][i] + bv);
    }
  }
}

// ------- mid/final MFMA dual GEMM, bf16 input, LDS-free --------------------
// TFP8: t out fp8 (layer 1) else bf16 (layer 2). RB16: r out bf16 else fp32.

template <int DOUT, bool TFP8, bool RB16>
__global__ __launch_bounds__(256) void gemm_mfma(const unsigned short* __restrict__ Hm,
                                                 const unsigned short* __restrict__ Wf,
                                                 const float* __restrict__ bias,
                                                 void* __restrict__ t_out,
                                                 void* __restrict__ r_out, int N) {
  constexpr int NTT = DOUT / 16;
  constexpr int ROWB = TFP8 ? DOUT : DOUT * 2;   // t row bytes (always 64 here)
  const int tid = threadIdx.x;
  if (blockIdx.x == 0 && tid < ROWB / 4)        // zero sentinel row N of t
    ((unsigned*)((char*)t_out + (size_t)N * ROWB))[tid] = 0u;
  const int wv = tid >> 6, lane = tid & 63;
  const int q = lane >> 4, m = lane & 15;
  const int row = blockIdx.x * 64 + wv * 16 + m;
  const int rowc = row < N ? row : N - 1;
  const s16x8 a0 = *(const s16x8*)&Hm[(size_t)rowc * 64 + q * 8];
  const s16x8 a1 = *(const s16x8*)&Hm[(size_t)rowc * 64 + 32 + q * 8];

  f32x4 acc[2 * NTT];
#pragma unroll
  for (int c = 0; c < 2 * NTT; ++c) acc[c] = (f32x4){0.f, 0.f, 0.f, 0.f};
#pragma unroll
  for (int c = 0; c < 2 * NTT; ++c) {
    s16x8 b0 = *(const s16x8*)&Wf[(c * 2 + 0) * 512 + lane * 8];
    s16x8 b1 = *(const s16x8*)&Wf[(c * 2 + 1) * 512 + lane * 8];
    acc[c] = __builtin_amdgcn_mfma_f32_16x16x32_bf16(a0, b0, acc[c], 0, 0, 0);
    acc[c] = __builtin_amdgcn_mfma_f32_16x16x32_bf16(a1, b1, acc[c], 0, 0, 0);
  }

  const int orow = blockIdx.x * 64 + wv * 16 + q * 4;
#pragma unroll
  for (int c = 0; c < NTT; ++c) {
#pragma unroll
    for (int i = 0; i < 4; ++i) {
      int r_ = orow + i;
      if (r_ < N) {
        if (TFP8)
          ((unsigned char*)t_out)[(size_t)r_ * DOUT + c * 16 + m] = f2fp8(acc[c][i]);
        else
          ((unsigned short*)t_out)[(size_t)r_ * DOUT + c * 16 + m] = f2bf(acc[c][i]);
      }
    }
  }
#pragma unroll
  for (int c = 0; c < NTT; ++c) {
    float bv = bias[c * 16 + m];
#pragma unroll
    for (int i = 0; i < 4; ++i) {
      int r_ = orow + i;
      if (r_ < N) {
        if (RB16)
          ((unsigned short*)r_out)[(size_t)r_ * DOUT + c * 16 + m] =
              f2bf(acc[NTT + c][i] + bv);
        else
          ((float*)r_out)[(size_t)r_ * DOUT + c * 16 + m] = acc[NTT + c][i] + bv;
      }
    }
  }
}

// ------- gather (fp8 t): h = bf16(elu(deg_inv * sum t[src] + r)) -----------
// 8 lanes/node, uint2/lane = 8 fp8 feats; row = 64B = 1 line. 2-stage
// pipeline (R18, neutral-but-harmless); packed int2 meta (one node-load).

__global__ __launch_bounds__(256) void gather_fp8(const uint2* __restrict__ t,
                                                  const unsigned short* __restrict__ r,
                                                  const int2* __restrict__ meta,
                                                  const int* __restrict__ colidx,
                                                  unsigned short* __restrict__ Xout,
                                                  int N) {
  int node = blockIdx.x * 32 + (threadIdx.x >> 3);
  int lane = threadIdx.x & 7;
  if (node >= N) return;
  const int2 mt = meta[node];
  const int b = mt.x;
  const int pc = mt.y & 0xFFFF;
  const int vr = mt.y >> 16;
  const int e = b + pc;                        // padded, multiple of 4
  float s[8];
#pragma unroll
  for (int k = 0; k < 8; ++k) s[k] = 0.f;
  int i = b;
  if (i + 8 <= e) {
    i32x4 c0 = *(const i32x4*)&colidx[i];
    i32x4 c1 = *(const i32x4*)&colidx[i + 4];
    uint2 va[8];
    va[0] = t[(size_t)c0.x * 8 + lane];
    va[1] = t[(size_t)c0.y * 8 + lane];
    va[2] = t[(size_t)c0.z * 8 + lane];
    va[3] = t[(size_t)c0.w * 8 + lane];
    va[4] = t[(size_t)c1.x * 8 + lane];
    va[5] = t[(size_t)c1.y * 8 + lane];
    va[6] = t[(size_t)c1.z * 8 + lane];
    va[7] = t[(size_t)c1.w * 8 + lane];
    while (i + 16 <= e) {
      i32x4 n0 = *(const i32x4*)&colidx[i + 8];
      i32x4 n1 = *(const i32x4*)&colidx[i + 12];
      uint2 vb[8];
      vb[0] = t[(size_t)n0.x * 8 + lane];
      vb[1] = t[(size_t)n0.y * 8 + lane];
      vb[2] = t[(size_t)n0.z * 8 + lane];
      vb[3] = t[(size_t)n0.w * 8 + lane];
      vb[4] = t[(size_t)n1.x * 8 + lane];
      vb[5] = t[(size_t)n1.y * 8 + lane];
      vb[6] = t[(size_t)n1.z * 8 + lane];
      vb[7] = t[(size_t)n1.w * 8 + lane];
#pragma unroll
      for (int j = 0; j < 8; ++j) {
        f32x2 p0 = __builtin_amdgcn_cvt_pk_f32_fp8((int)va[j].x, false);
        f32x2 p1 = __builtin_amdgcn_cvt_pk_f32_fp8((int)va[j].x, true);
        f32x2 p2 = __builtin_amdgcn_cvt_pk_f32_fp8((int)va[j].y, false);
        f32x2 p3 = __builtin_amdgcn_cvt_pk_f32_fp8((int)va[j].y, true);
        s[0] += p0[0]; s[1] += p0[1]; s[2] += p1[0]; s[3] += p1[1];
        s[4] += p2[0]; s[5] += p2[1]; s[6] += p3[0]; s[7] += p3[1];
      }
#pragma unroll
      for (int j = 0; j < 8; ++j) va[j] = vb[j];
      i += 8;
    }
#pragma unroll
    for (int j = 0; j < 8; ++j) {
      f32x2 p0 = __builtin_amdgcn_cvt_pk_f32_fp8((int)va[j].x, false);
      f32x2 p1 = __builtin_amdgcn_cvt_pk_f32_fp8((int)va[j].x, true);
      f32x2 p2 = __builtin_amdgcn_cvt_pk_f32_fp8((int)va[j].y, false);
      f32x2 p3 = __builtin_amdgcn_cvt_pk_f32_fp8((int)va[j].y, true);
      s[0] += p0[0]; s[1] += p0[1]; s[2] += p1[0]; s[3] += p1[1];
      s[4] += p2[0]; s[5] += p2[1]; s[6] += p3[0]; s[7] += p3[1];
    }
    i += 8;
  }
  if (i < e) {                                 // exactly 4 remain
    i32x4 c0 = *(const i32x4*)&colidx[i];
    uint2 v[4];
    v[0] = t[(size_t)c0.x * 8 + lane];
    v[1] = t[(size_t)c0.y * 8 + lane];
    v[2] = t[(size_t)c0.z * 8 + lane];
    v[3] = t[(size_t)c0.w * 8 + lane];
#pragma unroll
    for (int j = 0; j < 4; ++j) {
      f32x2 p0 = __builtin_amdgcn_cvt_pk_f32_fp8((int)v[j].x, false);
      f32x2 p1 = __builtin_amdgcn_cvt_pk_f32_fp8((int)v[j].x, true);
      f32x2 p2 = __builtin_amdgcn_cvt_pk_f32_fp8((int)v[j].y, false);
      f32x2 p3 = __builtin_amdgcn_cvt_pk_f32_fp8((int)v[j].y, true);
      s[0] += p0[0]; s[1] += p0[1]; s[2] += p1[0]; s[3] += p1[1];
      s[4] += p2[0]; s[5] += p2[1]; s[6] += p3[0]; s[7] += p3[1];
    }
  }
  const float dv = 1.0f / (float)(vr > 1 ? vr : 1);
  const s16x8 rv = *(const s16x8*)&r[(size_t)node * 64 + lane * 8];
  s16x8 hv;
#pragma unroll
  for (int k = 0; k < 8; ++k) {
    float ak = s[k] * dv + bf2f((unsigned short)rv[k]);
    ak = ak > 0.f ? ak : (expf(ak) - 1.f);
    hv[k] = (short)f2bf(ak);
  }
  *(s16x8*)&Xout[(size_t)node * 64 + lane * 8] = hv;
}

// ------- final gather: out = deg_inv * sum t2[src] + r[dst], t2 bf16 -------

__global__ __launch_bounds__(256) void gather_out(const uint2* __restrict__ t,
                                                  const float* __restrict__ r,
                                                  const int2* __restrict__ meta,
                                                  const int* __restrict__ colidx,
                                                  float* __restrict__ out, int N) {
  int node = blockIdx.x * 32 + (threadIdx.x >> 3);
  int lane = threadIdx.x & 7;
  if (node >= N) return;
  const int2 mt = meta[node];
  const int b = mt.x;
  const int pc = mt.y & 0xFFFF;
  const int vr = mt.y >> 16;
  const int e = b + pc;                // padded, multiple of 4
  float s0 = 0.f, s1 = 0.f, s2 = 0.f, s3 = 0.f;
  int i = b;
  if (i + 8 <= e) {
    i32x4 c0 = *(const i32x4*)&colidx[i];
    i32x4 c1 = *(const i32x4*)&colidx[i + 4];
    uint2 va[8];
    va[0] = t[(size_t)c0.x * 8 + lane];
    va[1] = t[(size_t)c0.y * 8 + lane];
    va[2] = t[(size_t)c0.z * 8 + lane];
    va[3] = t[(size_t)c0.w * 8 + lane];
    va[4] = t[(size_t)c1.x * 8 + lane];
    va[5] = t[(size_t)c1.y * 8 + lane];
    va[6] = t[(size_t)c1.z * 8 + lane];
    va[7] = t[(size_t)c1.w * 8 + lane];
    while (i + 16 <= e) {
      i32x4 n0 = *(const i32x4*)&colidx[i + 8];
      i32x4 n1 = *(const i32x4*)&colidx[i + 12];
      uint2 vb[8];
      vb[0] = t[(size_t)n0.x * 8 + lane];
      vb[1] = t[(size_t)n0.y * 8 + lane];
      vb[2] = t[(size_t)n0.z * 8 + lane];
      vb[3] = t[(size_t)n0.w * 8 + lane];
      vb[4] = t[(size_t)n1.x * 8 + lane];
      vb[5] = t[(size_t)n1.y * 8 + lane];
      vb[6] = t[(size_t)n1.z * 8 + lane];
      vb[7] = t[(size_t)n1.w * 8 + lane];
#pragma unroll
      for (int j = 0; j < 8; ++j) {
        s0 += bf2f((unsigned short)(va[j].x & 0xFFFFu));
        s1 += bf2f((unsigned short)(va[j].x >> 16));
        s2 += bf2f((unsigned short)(va[j].y & 0xFFFFu));
        s3 += bf2f((unsigned short)(va[j].y >> 16));
      }
#pragma unroll
      for (int j = 0; j < 8; ++j) va[j] = vb[j];
      i += 8;
    }
#pragma unroll
    for (int j = 0; j < 8; ++j) {
      s0 += bf2f((unsigned short)(va[j].x & 0xFFFFu));
      s1 += bf2f((unsigned short)(va[j].x >> 16));
      s2 += bf2f((unsigned short)(va[j].y & 0xFFFFu));
      s3 += bf2f((unsigned short)(va[j].y >> 16));
    }
    i += 8;
  }
  if (i < e) {                          // exactly 4 remain
    i32x4 c0 = *(const i32x4*)&colidx[i];
    uint2 v[4];
    v[0] = t[(size_t)c0.x * 8 + lane];
    v[1] = t[(size_t)c0.y * 8 + lane];
    v[2] = t[(size_t)c0.z * 8 + lane];
    v[3] = t[(size_t)c0.w * 8 + lane];
#pragma unroll
    for (int j = 0; j < 4; ++j) {
      s0 += bf2f((unsigned short)(v[j].x & 0xFFFFu));
      s1 += bf2f((unsigned short)(v[j].x >> 16));
      s2 += bf2f((unsigned short)(v[j].y & 0xFFFFu));
      s3 += bf2f((unsigned short)(v[j].y >> 16));
    }
  }
  const float dv = 1.0f / (float)(vr > 1 ? vr : 1);
  float4 rv = *(const float4*)&r[(size_t)node * 32 + 4 * lane];
  *(float4*)&out[(size_t)node * 32 + 4 * lane] =
      make_float4(s0 * dv + rv.x, s1 * dv + rv.y, s2 * dv + rv.z, s3 * dv + rv.w);
}

// ---------------- launch ----------------

extern "C" void kernel_launch(void* const* d_in, const int* in_sizes, int n_in,
                              void* d_out, int out_size, void* d_ws, size_t ws_size,
                              hipStream_t stream) {
  const float* x   = (const float*)d_in[0];
  const int*   ei  = (const int*)d_in[1];
  const float* Wl0 = (const float*)d_in[2];
  const float* Wr0 = (const float*)d_in[3];
  const float* b0  = (const float*)d_in[4];
  const float* Wl1 = (const float*)d_in[5];
  const float* Wr1 = (const float*)d_in[6];
  const float* b1  = (const float*)d_in[7];
  const float* Wl2 = (const float*)d_in[8];
  const float* Wr2 = (const float*)d_in[9];
  const float* b2  = (const float*)d_in[10];
  float* out = (float*)d_out;

  const int N = in_sizes[0] / 64;   // 100000
  const int E = in_sizes[1] / 2;    // 1600000
  const int* srcv = ei;
  const int* dstv = ei + E;
  const int NSB = (N + SBW - 1) >> LOGSBW;   // 391

  auto al = [](size_t v) { return (v + 255) & ~(size_t)255; };
  char* w = (char*)d_ws;
  size_t oBcur = 0;
  size_t oMeta = oBcur + al(4 * (size_t)NSB);
  size_t oWsw  = oMeta + al(8 * (size_t)N);
  size_t oBin  = oWsw + al(2 * 20480);
  size_t oCol  = oBin + al(4 * (size_t)NSB * CAPS);
  size_t oP8   = oCol + al(4 * (size_t)NSB * CAPSP);
  size_t oP16  = oP8 + al((size_t)(N + 1) * 64);   // fp8 t0/t1 (+sentinel row)
  size_t oX    = oP16 + al((size_t)(N + 1) * 64);  // bf16 t2 (+sentinel row)
  size_t oR    = oX + al(2 * (size_t)N * 64);      // bf16 h buffer
  // total = oR + 2*N*64  (~55 MiB); r buffer: bf16 [N][64] or fp32 [N][32]

  int*            bcur     = (int*)(w + oBcur);
  int2*           meta     = (int2*)(w + oMeta);
  unsigned short* Wsw      = (unsigned short*)(w + oWsw); // swizzled weights
  unsigned*       coarse   = (unsigned*)(w + oBin);
  int*            colidx   = (int*)(w + oCol);
  unsigned char*  P8       = (unsigned char*)(w + oP8);   // fp8 t0/t1
  unsigned short* P16      = (unsigned short*)(w + oP16); // bf16 t2
  unsigned short* X        = (unsigned short*)(w + oX);   // bf16 h
  unsigned short* Rb       = (unsigned short*)(w + oR);   // bf16 r (L0/L1)
  float*          Rf       = (float*)(w + oR);            // fp32 r (L2)

  int bbl = (E + CHK - 1) / CHK;   // 782
  int gb = (N + 63) / 64;          // 1563
  int ggb = (N + 31) / 32;         // 3125

  hipMemsetAsync(bcur, 0, (size_t)NSB * 4, stream);
  bin_stage<<<bbl + 40, 256, 0, stream>>>(srcv, dstv, bcur, coarse, NSB, E,
                                          Wl0, Wr0, Wl1, Wr1, Wl2, Wr2, Wsw);
  // CSR build (blocks [0,NSB)) overlapped with layer-0 GEMM (blocks [NSB,..))
  csr_gemm0<<<NSB + gb, 256, 0, stream>>>(coarse, bcur, meta, colidx, x, Wsw,
                                          b0, P8, Rb, N, NSB);
  gather_fp8<<<ggb, 256, 0, stream>>>((const uint2*)P8, Rb, meta, colidx, X, N);
  // layer 1: X -> t1 (fp8 P8), r1 (bf16 Rb)
  gemm_mfma<64, true, true><<<gb, 256, 0, stream>>>(X, Wsw + 8192, b1, P8, Rb, N);
  gather_fp8<<<ggb, 256, 0, stream>>>((const uint2*)P8, Rb, meta, colidx, X, N);
  // layer 2: X -> t2 (bf16 P16), r2 (fp32 Rf, [N][32])
  gemm_mfma<32, false, false><<<gb, 256, 0, stream>>>(X, Wsw + 16384, b2, P16, Rf, N);
  gather_out<<<ggb, 256, 0, stream>>>((const uint2*)P16, Rf, meta, colidx, out, N);
}